// Round 9
// baseline (430.357 us; speedup 1.0000x reference)
//
#include <hip/hip_runtime.h>
#include <hip/hip_bf16.h>
#include <math.h>
#include <float.h>

#define B_    32
#define C_    1536
#define T_    2000
#define BOT_  128
#define EPS_  1e-4f

#define TC2   32    // t-chunk per block
#define NT2   63    // ceil(2000/32)

typedef __attribute__((ext_vector_type(8))) short short8;
typedef __attribute__((ext_vector_type(4))) short short4v;
typedef __attribute__((ext_vector_type(4))) float f32x4;

static __device__ __forceinline__ unsigned short f2bf(float f) {
    unsigned u = __float_as_uint(f);
    u += 0x7FFFu + ((u >> 16) & 1u);           // RTNE
    return (unsigned short)(u >> 16);
}
static __device__ __forceinline__ float bf2f(unsigned short u) {
    return __uint_as_float(((unsigned)u) << 16);
}

// ---------------------------------------------------------------------------
// K1: per-(b,c) mean and unbiased std over T (fp32 exact).
// ---------------------------------------------------------------------------
__global__ __launch_bounds__(256) void stats_kernel(
    const float* __restrict__ x, float* __restrict__ mean_s, float* __restrict__ std_s) {
    const int row = blockIdx.x;                 // b*C + c
    const float4* x4 = reinterpret_cast<const float4*>(x + (size_t)row * T_);  // 500 vec4
    float s1 = 0.f, s2 = 0.f;
    for (int i = threadIdx.x; i < T_ / 4; i += 256) {
        float4 v = x4[i];
        s1 += v.x + v.y + v.z + v.w;
        s2 = fmaf(v.x, v.x, fmaf(v.y, v.y, fmaf(v.z, v.z, fmaf(v.w, v.w, s2))));
    }
    #pragma unroll
    for (int off = 32; off; off >>= 1) {
        s1 += __shfl_xor(s1, off);
        s2 += __shfl_xor(s2, off);
    }
    __shared__ float ls1[4], ls2[4];
    const int wave = threadIdx.x >> 6, lane = threadIdx.x & 63;
    if (lane == 0) { ls1[wave] = s1; ls2[wave] = s2; }
    __syncthreads();
    if (threadIdx.x == 0) {
        s1 = ls1[0] + ls1[1] + ls1[2] + ls1[3];
        s2 = ls2[0] + ls2[1] + ls2[2] + ls2[3];
        float mean = s1 / (float)T_;
        float var  = (s2 - s1 * mean) / (float)(T_ - 1);
        mean_s[row] = mean;
        std_s[row]  = sqrtf(fmaxf(var, EPS_));
    }
}

// ---------------------------------------------------------------------------
// K1b: convert W1[:, :C] and W2 to bf16.
// ---------------------------------------------------------------------------
__global__ __launch_bounds__(256) void cvt_kernel(
    const float* __restrict__ W1, const float* __restrict__ W2,
    unsigned short* __restrict__ W1b, unsigned short* __restrict__ W2b) {
    int idx = blockIdx.x * 256 + threadIdx.x;
    if (idx < BOT_ * C_) {
        int o = idx / C_, c = idx - o * C_;
        W1b[idx] = f2bf(W1[(size_t)o * (3 * C_) + c]);
        W2b[idx] = f2bf(W2[idx]);
    }
}

// ---------------------------------------------------------------------------
// K2: cb[b][o] = b1[o] + sum_c W1[o][C+c]*mean[b][c] + W1[o][2C+c]*std[b][c]
// ---------------------------------------------------------------------------
__global__ __launch_bounds__(128) void cb_kernel(
    const float* __restrict__ W1, const float* __restrict__ b1,
    const float* __restrict__ mean_s, const float* __restrict__ std_s,
    float* __restrict__ cb) {
    __shared__ float ml[C_];
    __shared__ float sl[C_];
    const int b = blockIdx.x;
    for (int c = threadIdx.x; c < C_; c += 128) {
        ml[c] = mean_s[(size_t)b * C_ + c];
        sl[c] = std_s[(size_t)b * C_ + c];
    }
    __syncthreads();
    const int o = threadIdx.x;
    const float* wm = W1 + (size_t)o * (3 * C_) + C_;
    const float* ws = wm + C_;
    float am0 = 0.f, am1 = 0.f, as0 = 0.f, as1 = 0.f;
    for (int c = 0; c < C_; c += 2) {
        am0 = fmaf(wm[c],     ml[c],     am0);
        am1 = fmaf(wm[c + 1], ml[c + 1], am1);
        as0 = fmaf(ws[c],     sl[c],     as0);
        as1 = fmaf(ws[c + 1], sl[c + 1], as1);
    }
    cb[(size_t)b * BOT_ + o] = b1[o] + (am0 + am1) + (as0 + as1);
}

// ---------------------------------------------------------------------------
// K3 (fused, barrier-minimal): per (b, 32-t chunk), 512 threads / 8 waves:
//   stage: full x slice 32t x 1536c -> LDS bf16 (swizzled b128 writes), ONCE.
//   phase 1 (no barriers): 48 k-steps, h[o,t] = relu(W1.x + cb); W1 A-frags
//     from L2, x B-frags from LDS; each wave owns 16 o-rows. h -> Hl (LDS).
//   phase 2 (no barriers): 12 c-iters of 128; swapped MFMA (A=Hl t-rows,
//     B=W2 c-rows) so lane=c, regs=t; Hl A-frags hoisted (read once);
//     max-free exp (|L|<~3, b2 cancels); x for S1/S2 from LDS; 2-shfl
//     reduce; (Z,S1,S2) partials to ws.
// Exactly 2 barriers per block. x touches HBM once in this kernel.
// ---------------------------------------------------------------------------
__global__ __launch_bounds__(512) void fused_main(
    const float* __restrict__ x, const unsigned short* __restrict__ W1b,
    const unsigned short* __restrict__ W2b, const float* __restrict__ cb,
    float* __restrict__ part) {
    const int b   = blockIdx.y;
    const int ts  = blockIdx.x;
    const int t0  = ts * TC2;
    const int tid = threadIdx.x;
    const int lane = tid & 63;
    const int w   = tid >> 6;          // 0..7
    const int g   = lane >> 4, li = lane & 15;

    __shared__ __align__(16) unsigned short Xf[TC2 * C_];    // 96KB, swizzled
    __shared__ __align__(16) unsigned short Hl[TC2 * BOT_];  // 8KB, swizzled

    const float* xb = x + (size_t)b * C_ * T_;

    // ---- stage x once: thread owns (t = lane&31, 96 c-values) ----
    {
        const int t  = lane & 31;
        const int tg = t0 + t;
        const bool tv = tg < T_;
        const int cb0 = w * 192 + (lane >> 5) * 96;
        const float* xp = xb + tg;
        #pragma unroll
        for (int j = 0; j < 12; ++j) {
            short8 pk;
            #pragma unroll
            for (int e = 0; e < 8; ++e) {
                float v = tv ? xp[(size_t)(cb0 + j * 8 + e) * T_] : 0.f;
                pk[e] = (short)f2bf(v);
            }
            const int c8 = (cb0 >> 3) + j;
            *reinterpret_cast<short8*>(&Xf[t * C_ + ((c8 ^ (t & 7)) << 3)]) = pk;
        }
    }
    __syncthreads();

    // ---- phase 1: wave w owns o-rows [w*16, w*16+16), all 32 t ----
    const int tA = li, tB = 16 + li;
    f32x4 hacc0 = (f32x4){0.f, 0.f, 0.f, 0.f};
    f32x4 hacc1 = (f32x4){0.f, 0.f, 0.f, 0.f};
    {
        const unsigned short* w1row = W1b + (size_t)(w * 16 + li) * C_ + g * 8;
        #pragma unroll 4
        for (int ks = 0; ks < 48; ++ks) {
            short8 a  = *reinterpret_cast<const short8*>(w1row + ks * 32);
            short8 b0 = *reinterpret_cast<const short8*>(
                &Xf[tA * C_ + (((ks * 4 + g) ^ (tA & 7)) << 3)]);
            short8 b1 = *reinterpret_cast<const short8*>(
                &Xf[tB * C_ + (((ks * 4 + g) ^ (tB & 7)) << 3)]);
            hacc0 = __builtin_amdgcn_mfma_f32_16x16x32_bf16(a, b0, hacc0, 0, 0, 0);
            hacc1 = __builtin_amdgcn_mfma_f32_16x16x32_bf16(a, b1, hacc1, 0, 0, 0);
        }
    }
    // epilogue: +cb, relu, bf16 -> Hl[t][o] (swizzled 8B writes)
    {
        const int o0 = w * 16 + g * 4;
        const float4 cbv = *reinterpret_cast<const float4*>(cb + (size_t)b * BOT_ + o0);
        const int sb = o0 >> 3, off = o0 & 7;
        short4v p0, p1;
        p0[0] = (short)f2bf(fmaxf(hacc0[0] + cbv.x, 0.f));
        p0[1] = (short)f2bf(fmaxf(hacc0[1] + cbv.y, 0.f));
        p0[2] = (short)f2bf(fmaxf(hacc0[2] + cbv.z, 0.f));
        p0[3] = (short)f2bf(fmaxf(hacc0[3] + cbv.w, 0.f));
        p1[0] = (short)f2bf(fmaxf(hacc1[0] + cbv.x, 0.f));
        p1[1] = (short)f2bf(fmaxf(hacc1[1] + cbv.y, 0.f));
        p1[2] = (short)f2bf(fmaxf(hacc1[2] + cbv.z, 0.f));
        p1[3] = (short)f2bf(fmaxf(hacc1[3] + cbv.w, 0.f));
        *reinterpret_cast<short4v*>(&Hl[tA * BOT_ + ((sb ^ (tA & 7)) << 3) + off]) = p0;
        *reinterpret_cast<short4v*>(&Hl[tB * BOT_ + ((sb ^ (tB & 7)) << 3) + off]) = p1;
    }
    __syncthreads();

    // ---- phase 2: lane = c; Hl A-frags hoisted (same for all 12 iters) ----
    short8 af0[4], af1[4];
    #pragma unroll
    for (int ks = 0; ks < 4; ++ks) {
        af0[ks] = *reinterpret_cast<const short8*>(
            &Hl[tA * BOT_ + (((ks * 4 + g) ^ (tA & 7)) << 3)]);
        af1[ks] = *reinterpret_cast<const short8*>(
            &Hl[tB * BOT_ + (((ks * 4 + g) ^ (tB & 7)) << 3)]);
    }

    float* pbase = part + ((size_t)(b * NT2 + ts) * 3) * C_;

    for (int it = 0; it < 12; ++it) {
        const int c = it * 128 + w * 16 + li;
        // B-frags: W2b row c (k = o contiguous), from L2
        short8 bfr[4];
        #pragma unroll
        for (int ks = 0; ks < 4; ++ks)
            bfr[ks] = *reinterpret_cast<const short8*>(
                W2b + (size_t)c * BOT_ + ks * 32 + g * 8);
        // logits: D[t][c], t in regs, c = lane
        f32x4 l0 = (f32x4){0.f, 0.f, 0.f, 0.f};
        f32x4 l1 = (f32x4){0.f, 0.f, 0.f, 0.f};
        #pragma unroll
        for (int ks = 0; ks < 4; ++ks) {
            l0 = __builtin_amdgcn_mfma_f32_16x16x32_bf16(af0[ks], bfr[ks], l0, 0, 0, 0);
            l1 = __builtin_amdgcn_mfma_f32_16x16x32_bf16(af1[ks], bfr[ks], l1, 0, 0, 0);
        }
        // max-free exp + in-register t-accumulation (x from LDS, bf16)
        float Z = 0.f, S1 = 0.f, S2 = 0.f;
        #pragma unroll
        for (int r = 0; r < 4; ++r) {
            int tl = g * 4 + r;
            float p = __expf(l0[r]);
            p = (t0 + tl < T_) ? p : 0.f;
            float xx = bf2f(Xf[tl * C_ + (((c >> 3) ^ (tl & 7)) << 3) + (c & 7)]);
            Z += p;
            S1 = fmaf(xx, p, S1);
            S2 = fmaf(xx * xx, p, S2);
        }
        #pragma unroll
        for (int r = 0; r < 4; ++r) {
            int tl = 16 + g * 4 + r;
            float p = __expf(l1[r]);
            p = (t0 + tl < T_) ? p : 0.f;
            float xx = bf2f(Xf[tl * C_ + (((c >> 3) ^ (tl & 7)) << 3) + (c & 7)]);
            Z += p;
            S1 = fmaf(xx, p, S1);
            S2 = fmaf(xx * xx, p, S2);
        }
        // reduce across g (lanes ^16, ^32)
        Z  += __shfl_xor(Z, 16);  Z  += __shfl_xor(Z, 32);
        S1 += __shfl_xor(S1, 16); S1 += __shfl_xor(S1, 32);
        S2 += __shfl_xor(S2, 16); S2 += __shfl_xor(S2, 32);
        if (lane < 16) {
            pbase[c]          = Z;
            pbase[C_ + c]     = S1;
            pbase[2 * C_ + c] = S2;
        }
    }
}

// ---------------------------------------------------------------------------
// K4: fold the NT2 t-chunk partials, finalize wmean/wsd.
// ---------------------------------------------------------------------------
__global__ __launch_bounds__(256) void reduce_kernel(
    const float* __restrict__ part, float* __restrict__ out) {
    const int c = blockIdx.x * 256 + threadIdx.x;
    const int b = blockIdx.y;
    float Z = 0.f, S1 = 0.f, S2 = 0.f;
    for (int ts = 0; ts < NT2; ++ts) {
        const float* pb = part + ((size_t)(b * NT2 + ts) * 3) * C_ + c;
        Z  += pb[0];
        S1 += pb[C_];
        S2 += pb[2 * C_];
    }
    float wmean = S1 / Z;
    float wsd   = sqrtf(fmaxf(S2 / Z - wmean * wmean, EPS_));
    out[(size_t)b * (2 * C_) + c]      = wmean;
    out[(size_t)b * (2 * C_) + C_ + c] = wsd;
}

// ---------------------------------------------------------------------------
extern "C" void kernel_launch(void* const* d_in, const int* in_sizes, int n_in,
                              void* d_out, int out_size, void* d_ws, size_t ws_size,
                              hipStream_t stream) {
    const float* x  = (const float*)d_in[0];   // [B, C, T]
    const float* W1 = (const float*)d_in[1];   // [BOT, 3C]
    const float* b1 = (const float*)d_in[2];   // [BOT]
    const float* W2 = (const float*)d_in[3];   // [C, BOT]
    // b2 (d_in[4]) cancels in softmax over T
    float* out = (float*)d_out;                // [B, 2C]

    float* ws = (float*)d_ws;
    float* mean_s = ws;                                   // B*C
    float* std_s  = mean_s + (size_t)B_ * C_;             // B*C
    float* cb     = std_s  + (size_t)B_ * C_;             // B*BOT
    float* part   = cb + (size_t)B_ * BOT_;               // B*NT2*3*C (37MB)
    unsigned short* W1b = (unsigned short*)(part + (size_t)B_ * NT2 * 3 * C_);
    unsigned short* W2b = W1b + (size_t)BOT_ * C_;        // C*BOT

    stats_kernel<<<dim3(B_ * C_), 256, 0, stream>>>(x, mean_s, std_s);
    cvt_kernel<<<dim3((BOT_ * C_ + 255) / 256), 256, 0, stream>>>(W1, W2, W1b, W2b);
    cb_kernel<<<dim3(B_), 128, 0, stream>>>(W1, b1, mean_s, std_s, cb);
    fused_main<<<dim3(NT2, B_), 512, 0, stream>>>(x, W1b, W2b, cb, part);
    reduce_kernel<<<dim3(C_ / 256, B_), 256, 0, stream>>>(part, out);
}

// Round 10
// 407.488 us; speedup vs baseline: 1.0561x; 1.0561x over previous
//
#include <hip/hip_runtime.h>
#include <hip/hip_bf16.h>
#include <math.h>
#include <float.h>

#define B_    32
#define C_    1536
#define T_    2000
#define TP_   2048  // padded T for xt
#define BOT_  128
#define EPS_  1e-4f

#define CH    64    // c-chunk, phase 1
#define TC    64    // t-chunk per block
#define NTS   32    // 2048/64

typedef __attribute__((ext_vector_type(8))) short short8;
typedef __attribute__((ext_vector_type(4))) short short4v;
typedef __attribute__((ext_vector_type(4))) float f32x4;

static __device__ __forceinline__ unsigned short f2bf(float f) {
    unsigned u = __float_as_uint(f);
    u += 0x7FFFu + ((u >> 16) & 1u);           // RTNE
    return (unsigned short)(u >> 16);
}

// ---------------------------------------------------------------------------
// K1: per-(b,c) mean/std over T (fp32 exact) AND bf16 transpose
//     xt[b][t][c] (t padded to 2048 with zeros).
// Block = (64 c, b); wave w covers t-slice [it*64 + w*16, +16) per iter.
// Lane: c0=(lane&15)*4, tb=lane>>4. 4x4 register micro-transpose:
// 4 float4 loads along t (L2 absorbs the c-stride), 4 short4 stores along c.
// ---------------------------------------------------------------------------
__global__ __launch_bounds__(256) void stats_transpose(
    const float* __restrict__ x, float* __restrict__ mean_s, float* __restrict__ std_s,
    unsigned short* __restrict__ xt) {
    const int b = blockIdx.y, cb0 = blockIdx.x * 64;
    const int tid = threadIdx.x, lane = tid & 63, w = tid >> 6;
    const int c0 = (lane & 15) * 4, tb = lane >> 4;

    const float* xb = x + ((size_t)b * C_ + cb0) * T_;
    unsigned short* xo = xt + (size_t)b * TP_ * C_ + cb0;

    float s1[4] = {0.f, 0.f, 0.f, 0.f}, s2[4] = {0.f, 0.f, 0.f, 0.f};

    for (int it = 0; it < TP_ / 64; ++it) {
        const int tbase = it * 64 + w * 16 + tb * 4;
        f32x4 v[4];
        if (tbase < T_) {   // tbase%4==0 and T%4==0 -> full float4 valid
            #pragma unroll
            for (int k = 0; k < 4; ++k)
                v[k] = *reinterpret_cast<const f32x4*>(xb + (size_t)(c0 + k) * T_ + tbase);
        } else {
            #pragma unroll
            for (int k = 0; k < 4; ++k)
                v[k] = (f32x4){0.f, 0.f, 0.f, 0.f};
        }
        #pragma unroll
        for (int k = 0; k < 4; ++k) {
            s1[k] += (v[k][0] + v[k][1]) + (v[k][2] + v[k][3]);
            s2[k] = fmaf(v[k][0], v[k][0], fmaf(v[k][1], v[k][1],
                    fmaf(v[k][2], v[k][2], fmaf(v[k][3], v[k][3], s2[k]))));
        }
        #pragma unroll
        for (int j = 0; j < 4; ++j) {
            short4v pk;
            pk[0] = (short)f2bf(v[0][j]);
            pk[1] = (short)f2bf(v[1][j]);
            pk[2] = (short)f2bf(v[2][j]);
            pk[3] = (short)f2bf(v[3][j]);
            *reinterpret_cast<short4v*>(xo + (size_t)(tbase + j) * C_ + c0) = pk;
        }
    }

    // reduce over the 4 tb-groups (lanes ^16, ^32)
    #pragma unroll
    for (int k = 0; k < 4; ++k) {
        s1[k] += __shfl_xor(s1[k], 16); s1[k] += __shfl_xor(s1[k], 32);
        s2[k] += __shfl_xor(s2[k], 16); s2[k] += __shfl_xor(s2[k], 32);
    }
    __shared__ float sb[4][64][2];
    if (lane < 16) {
        #pragma unroll
        for (int k = 0; k < 4; ++k) {
            sb[w][c0 + k][0] = s1[k];
            sb[w][c0 + k][1] = s2[k];
        }
    }
    __syncthreads();
    if (tid < 64) {
        float S1 = sb[0][tid][0] + sb[1][tid][0] + sb[2][tid][0] + sb[3][tid][0];
        float S2 = sb[0][tid][1] + sb[1][tid][1] + sb[2][tid][1] + sb[3][tid][1];
        float mean = S1 / (float)T_;
        float var  = (S2 - S1 * mean) / (float)(T_ - 1);
        mean_s[(size_t)b * C_ + cb0 + tid] = mean;
        std_s[(size_t)b * C_ + cb0 + tid]  = sqrtf(fmaxf(var, EPS_));
    }
}

// ---------------------------------------------------------------------------
// K1b: convert W1[:, :C] and W2 to bf16.
// ---------------------------------------------------------------------------
__global__ __launch_bounds__(256) void cvt_kernel(
    const float* __restrict__ W1, const float* __restrict__ W2,
    unsigned short* __restrict__ W1b, unsigned short* __restrict__ W2b) {
    int idx = blockIdx.x * 256 + threadIdx.x;
    if (idx < BOT_ * C_) {
        int o = idx / C_, c = idx - o * C_;
        W1b[idx] = f2bf(W1[(size_t)o * (3 * C_) + c]);
        W2b[idx] = f2bf(W2[idx]);
    }
}

// ---------------------------------------------------------------------------
// K2: cb[b][o] = b1[o] + sum_c W1[o][C+c]*mean[b][c] + W1[o][2C+c]*std[b][c]
// ---------------------------------------------------------------------------
__global__ __launch_bounds__(128) void cb_kernel(
    const float* __restrict__ W1, const float* __restrict__ b1,
    const float* __restrict__ mean_s, const float* __restrict__ std_s,
    float* __restrict__ cb) {
    __shared__ float ml[C_];
    __shared__ float sl[C_];
    const int b = blockIdx.x;
    for (int c = threadIdx.x; c < C_; c += 128) {
        ml[c] = mean_s[(size_t)b * C_ + c];
        sl[c] = std_s[(size_t)b * C_ + c];
    }
    __syncthreads();
    const int o = threadIdx.x;
    const float* wm = W1 + (size_t)o * (3 * C_) + C_;
    const float* ws = wm + C_;
    float am0 = 0.f, am1 = 0.f, as0 = 0.f, as1 = 0.f;
    for (int c = 0; c < C_; c += 2) {
        am0 = fmaf(wm[c],     ml[c],     am0);
        am1 = fmaf(wm[c + 1], ml[c + 1], am1);
        as0 = fmaf(ws[c],     sl[c],     as0);
        as1 = fmaf(ws[c + 1], sl[c + 1], as1);
    }
    cb[(size_t)b * BOT_ + o] = b1[o] + (am0 + am1) + (as0 + as1);
}

// ---------------------------------------------------------------------------
// K3 (fused): per (b, 64-t chunk):
//  phase 1: h = relu(W1b.x + cb) via MFMA. Staging from xt[b][t][c] bf16:
//    2 coalesced b128 global loads + 2 swizzled b128 LDS writes per thread
//    per chunk (1-chunk register prefetch). No per-element cvt, no masking
//    (xt zero-padded to 2048).
//  phase 2: swapped-operand MFMA (A = Hl t-rows, B = W2 c-rows), lane=c,
//    regs=t: Z/S1/S2 in-register over t; max-free exp (|L|<~3, b2 cancels);
//    xv fp32 float4 from x (L2/L3-warm); 2-shfl reduce; partials to ws.
// 4 waves, grid (NTS, B), 24KB LDS -> ~6 blocks/CU.
// ---------------------------------------------------------------------------
__global__ __launch_bounds__(256) void fused_main(
    const float* __restrict__ x, const unsigned short* __restrict__ xt,
    const unsigned short* __restrict__ W1b, const unsigned short* __restrict__ W2b,
    const float* __restrict__ cb, float* __restrict__ part) {
    const int b   = blockIdx.y;
    const int ts  = blockIdx.x;
    const int t0  = ts * TC;
    const int tid = threadIdx.x;
    const int lane = tid & 63;
    const int w   = tid >> 6;          // 0..3
    const int g   = lane >> 4, li = lane & 15;

    __shared__ __align__(16) unsigned short Xb[64 * 64];    // [t][c] swizzled, 8KB
    __shared__ __align__(16) unsigned short Hl[64 * 128];   // [t][o] swizzled, 16KB

    const float* xb = x + (size_t)b * C_ * T_;
    const unsigned short* xtb = xt + (size_t)b * TP_ * C_;

    // staging coords: e = tid + 256*i -> t = e>>3, s = e&7
    const int st_t0 = tid >> 3, st_s0 = tid & 7;          // i = 0
    const int st_t1 = (tid + 256) >> 3, st_s1 = tid & 7;  // i = 1

    // ---------------- phase 1 ----------------
    f32x4 hacc[2][4];
    #pragma unroll
    for (int mi = 0; mi < 2; ++mi)
        #pragma unroll
        for (int ni = 0; ni < 4; ++ni)
            hacc[mi][ni] = (f32x4){0.f, 0.f, 0.f, 0.f};

    short8 xs0, xs1;
    xs0 = *reinterpret_cast<const short8*>(xtb + (size_t)(t0 + st_t0) * C_ + st_s0 * 8);
    xs1 = *reinterpret_cast<const short8*>(xtb + (size_t)(t0 + st_t1) * C_ + st_s1 * 8);

    for (int kc = 0; kc < C_; kc += CH) {
        __syncthreads();   // prior-iter Xb reads complete
        *reinterpret_cast<short8*>(&Xb[st_t0 * 64 + ((st_s0 ^ (st_t0 & 7)) << 3)]) = xs0;
        *reinterpret_cast<short8*>(&Xb[st_t1 * 64 + ((st_s1 ^ (st_t1 & 7)) << 3)]) = xs1;
        // prefetch next chunk (in flight during MFMA)
        if (kc + CH < C_) {
            xs0 = *reinterpret_cast<const short8*>(
                xtb + (size_t)(t0 + st_t0) * C_ + kc + CH + st_s0 * 8);
            xs1 = *reinterpret_cast<const short8*>(
                xtb + (size_t)(t0 + st_t1) * C_ + kc + CH + st_s1 * 8);
        }
        __syncthreads();
        // wave w owns o-rows [w*32, w*32+32); K=64 in 2 steps of 32
        #pragma unroll
        for (int ks = 0; ks < 2; ++ks) {
            short8 a[2], bb4[4];
            #pragma unroll
            for (int mi = 0; mi < 2; ++mi)
                a[mi] = *reinterpret_cast<const short8*>(
                    W1b + (size_t)(w * 32 + mi * 16 + li) * C_ + kc + ks * 32 + g * 8);
            #pragma unroll
            for (int ni = 0; ni < 4; ++ni) {
                int t = ni * 16 + li;
                bb4[ni] = *reinterpret_cast<const short8*>(
                    &Xb[t * 64 + (((ks * 4 + g) ^ (t & 7)) << 3)]);
            }
            #pragma unroll
            for (int mi = 0; mi < 2; ++mi)
                #pragma unroll
                for (int ni = 0; ni < 4; ++ni)
                    hacc[mi][ni] = __builtin_amdgcn_mfma_f32_16x16x32_bf16(a[mi], bb4[ni], hacc[mi][ni], 0, 0, 0);
        }
    }

    // epilogue: +cb, relu, bf16 -> Hl[t][o] (swizzled, 8B writes)
    __syncthreads();
    #pragma unroll
    for (int mi = 0; mi < 2; ++mi) {
        const int ob = w * 32 + mi * 16 + g * 4;
        const float4 cbv = *reinterpret_cast<const float4*>(cb + (size_t)b * BOT_ + ob);
        #pragma unroll
        for (int ni = 0; ni < 4; ++ni) {
            int t = ni * 16 + li;
            short4v pk;
            pk[0] = (short)f2bf(fmaxf(hacc[mi][ni][0] + cbv.x, 0.f));
            pk[1] = (short)f2bf(fmaxf(hacc[mi][ni][1] + cbv.y, 0.f));
            pk[2] = (short)f2bf(fmaxf(hacc[mi][ni][2] + cbv.z, 0.f));
            pk[3] = (short)f2bf(fmaxf(hacc[mi][ni][3] + cbv.w, 0.f));
            *reinterpret_cast<short4v*>(
                &Hl[t * 128 + (((w * 4 + mi * 2 + (g >> 1)) ^ (t & 7)) << 3) + (g & 1) * 4]) = pk;
        }
    }
    __syncthreads();

    // ---------------- phase 2: swapped MFMA, lane = c ----------------
    float* pbase = part + ((size_t)(b * NTS + ts) * 3) * C_;

    for (int ccb = 0; ccb < C_; ccb += 64) {
        const int c = ccb + w * 16 + li;
        // x fp32 loads for weighted sums (L2/L3-warm; float4 per ni)
        f32x4 xv[4];
        #pragma unroll
        for (int ni = 0; ni < 4; ++ni) {
            const int tg = t0 + ni * 16 + g * 4;
            const float* xp = xb + (size_t)c * T_ + tg;
            if (tg + 4 <= T_) {
                xv[ni] = *reinterpret_cast<const f32x4*>(xp);
            } else {
                #pragma unroll
                for (int r = 0; r < 4; ++r)
                    xv[ni][r] = (tg + r < T_) ? xp[r] : 0.f;
            }
        }
        // B-frags: W2b row c (k = o contiguous), from L2
        short8 bfr[4];
        #pragma unroll
        for (int ks = 0; ks < 4; ++ks)
            bfr[ks] = *reinterpret_cast<const short8*>(
                W2b + (size_t)c * BOT_ + ks * 32 + g * 8);
        // logits: D[t][c], t in regs, c = lane
        f32x4 lacc[4];
        #pragma unroll
        for (int ni = 0; ni < 4; ++ni) lacc[ni] = (f32x4){0.f, 0.f, 0.f, 0.f};
        #pragma unroll
        for (int ks = 0; ks < 4; ++ks) {
            short8 af[4];
            #pragma unroll
            for (int ni = 0; ni < 4; ++ni) {
                int t = ni * 16 + li;
                af[ni] = *reinterpret_cast<const short8*>(
                    &Hl[t * 128 + (((ks * 4 + g) ^ (t & 7)) << 3)]);
            }
            #pragma unroll
            for (int ni = 0; ni < 4; ++ni)
                lacc[ni] = __builtin_amdgcn_mfma_f32_16x16x32_bf16(af[ni], bfr[ks], lacc[ni], 0, 0, 0);
        }
        // max-free exp + in-register t-accumulation
        float Z = 0.f, S1 = 0.f, S2 = 0.f;
        #pragma unroll
        for (int ni = 0; ni < 4; ++ni)
            #pragma unroll
            for (int r = 0; r < 4; ++r) {
                int t = t0 + ni * 16 + g * 4 + r;
                float p = __expf(lacc[ni][r]);
                p = (t < T_) ? p : 0.f;
                float xx = xv[ni][r];
                Z += p;
                S1 = fmaf(xx, p, S1);
                S2 = fmaf(xx * xx, p, S2);
            }
        // reduce across g (lanes ^16, ^32)
        Z  += __shfl_xor(Z, 16);  Z  += __shfl_xor(Z, 32);
        S1 += __shfl_xor(S1, 16); S1 += __shfl_xor(S1, 32);
        S2 += __shfl_xor(S2, 16); S2 += __shfl_xor(S2, 32);
        if (lane < 16) {
            pbase[c]          = Z;
            pbase[C_ + c]     = S1;
            pbase[2 * C_ + c] = S2;
        }
    }
}

// ---------------------------------------------------------------------------
// K4: fold the NTS t-chunk partials, finalize wmean/wsd.
// ---------------------------------------------------------------------------
__global__ __launch_bounds__(256) void reduce_kernel(
    const float* __restrict__ part, float* __restrict__ out) {
    const int c = blockIdx.x * 256 + threadIdx.x;
    const int b = blockIdx.y;
    float Z = 0.f, S1 = 0.f, S2 = 0.f;
    for (int ts = 0; ts < NTS; ++ts) {
        const float* pb = part + ((size_t)(b * NTS + ts) * 3) * C_ + c;
        Z  += pb[0];
        S1 += pb[C_];
        S2 += pb[2 * C_];
    }
    float wmean = S1 / Z;
    float wsd   = sqrtf(fmaxf(S2 / Z - wmean * wmean, EPS_));
    out[(size_t)b * (2 * C_) + c]      = wmean;
    out[(size_t)b * (2 * C_) + C_ + c] = wsd;
}

// ---------------------------------------------------------------------------
extern "C" void kernel_launch(void* const* d_in, const int* in_sizes, int n_in,
                              void* d_out, int out_size, void* d_ws, size_t ws_size,
                              hipStream_t stream) {
    const float* x  = (const float*)d_in[0];   // [B, C, T]
    const float* W1 = (const float*)d_in[1];   // [BOT, 3C]
    const float* b1 = (const float*)d_in[2];   // [BOT]
    const float* W2 = (const float*)d_in[3];   // [C, BOT]
    // b2 (d_in[4]) cancels in softmax over T
    float* out = (float*)d_out;                // [B, 2C]

    float* ws = (float*)d_ws;
    float* mean_s = ws;                                   // B*C
    float* std_s  = mean_s + (size_t)B_ * C_;             // B*C
    float* cb     = std_s  + (size_t)B_ * C_;             // B*BOT
    float* part   = cb + (size_t)B_ * BOT_;               // B*NTS*3*C (18.9MB)
    unsigned short* W1b = (unsigned short*)(part + (size_t)B_ * NTS * 3 * C_);
    unsigned short* W2b = W1b + (size_t)BOT_ * C_;        // C*BOT
    unsigned short* xt  = W2b + (size_t)C_ * BOT_;        // B*TP*C bf16 (192MB)

    stats_transpose<<<dim3(C_ / 64, B_), 256, 0, stream>>>(x, mean_s, std_s, xt);
    cvt_kernel<<<dim3((BOT_ * C_ + 255) / 256), 256, 0, stream>>>(W1, W2, W1b, W2b);
    cb_kernel<<<dim3(B_), 128, 0, stream>>>(W1, b1, mean_s, std_s, cb);
    fused_main<<<dim3(NTS, B_), 256, 0, stream>>>(x, xt, W1b, W2b, cb, part);
    reduce_kernel<<<dim3(C_ / 256, B_), 256, 0, stream>>>(part, out);
}